// Round 3
// baseline (349.025 us; speedup 1.0000x reference)
//
#include <hip/hip_runtime.h>
#include <hip/hip_bf16.h>
#include <stdint.h>

#define NCOLS 8192
#define BS    256
#define NB    16

typedef float    f32x4  __attribute__((ext_vector_type(4)));
typedef short    bf16x8 __attribute__((ext_vector_type(8)));
typedef unsigned u32x4  __attribute__((ext_vector_type(4)));

// RNE-pack two fp32 into one dword of two bf16 (lo = first arg)
__device__ __forceinline__ unsigned pack2(float lo, float hi) {
  unsigned a = __builtin_bit_cast(unsigned, lo);
  unsigned b = __builtin_bit_cast(unsigned, hi);
  a += 0x7FFFu + ((a >> 16) & 1u);
  b += 0x7FFFu + ((b >> 16) & 1u);
  return (a >> 16) | (b & 0xFFFF0000u);
}

// Convert W (16x256x256 fp32) -> bf16 in ws. 8 elems/thread.
__global__ __launch_bounds__(256) void wcvt_kernel(const float* __restrict__ Wf,
                                                   unsigned* __restrict__ Wb) {
  int i = blockIdx.x * 256 + threadIdx.x;
  f32x4 a = ((const f32x4*)Wf)[2 * i];
  f32x4 c = ((const f32x4*)Wf)[2 * i + 1];
  u32x4 o;
  o.x = pack2(a.x, a.y); o.y = pack2(a.z, a.w);
  o.z = pack2(c.x, c.y); o.w = pack2(c.z, c.w);
  ((u32x4*)Wb)[i] = o;
}

// No LDS, no barriers. One wave owns (block b, 16 cols) x all 256 rows.
// B-frags straight from global X (fp32 -> bf16 in-register); A-frags from
// L2-resident bf16 W. acc = 16 m-tiles of 16x16.
template<bool USE_WS>
__global__ __launch_bounds__(256)
void bg_kernel(const float* __restrict__ X, const float* __restrict__ Wf,
               const unsigned short* __restrict__ Wb, float* __restrict__ out) {
  const int b    = blockIdx.y;
  const int t    = threadIdx.x;
  const int wid  = t >> 6;
  const int lane = t & 63;
  const int ln16 = lane & 15;
  const int quad = lane >> 4;
  const int n    = blockIdx.x * 64 + wid * 16 + ln16;  // this lane's output col

  const float* xcol = X + (size_t)b * BS * NCOLS + n;

  f32x4 acc[16] = {};

#pragma unroll
  for (int ks = 0; ks < 8; ++ks) {
    // ---- B-fragment: X[ks*32 + quad*8 + j][n], j = 0..7 (k-major in lane)
    const float* xp = xcol + (size_t)(ks * 32 + quad * 8) * NCOLS;
    float xv[8];
#pragma unroll
    for (int j = 0; j < 8; ++j) xv[j] = xp[(size_t)j * NCOLS];
    union { unsigned u[4]; bf16x8 v; } bb;
#pragma unroll
    for (int j = 0; j < 4; ++j) bb.u[j] = pack2(xv[2 * j], xv[2 * j + 1]);
    const bf16x8 bfr = bb.v;

    // ---- A-fragments: all 16 m-tiles of W[b]
#pragma unroll
    for (int mt = 0; mt < 16; ++mt) {
      const int m = mt * 16 + ln16;
      const size_t off = ((size_t)(b * BS + m)) * BS + ks * 32 + quad * 8;
      bf16x8 afr;
      if (USE_WS) {
        afr = *(const bf16x8*)(Wb + off);
      } else {
        f32x4 w0 = *(const f32x4*)(Wf + off);
        f32x4 w1 = *(const f32x4*)(Wf + off + 4);
        union { unsigned u[4]; bf16x8 v; } cv;
        cv.u[0] = pack2(w0.x, w0.y); cv.u[1] = pack2(w0.z, w0.w);
        cv.u[2] = pack2(w1.x, w1.y); cv.u[3] = pack2(w1.z, w1.w);
        afr = cv.v;
      }
      acc[mt] = __builtin_amdgcn_mfma_f32_16x16x32_bf16(afr, bfr, acc[mt], 0, 0, 0);
    }
  }

  // ---- epilogue: C/D layout col=lane&15 (== n), row = quad*4 + r
#pragma unroll
  for (int mt = 0; mt < 16; ++mt) {
    const int m = mt * 16 + quad * 4;
#pragma unroll
    for (int r = 0; r < 4; ++r)
      out[(size_t)(b * BS + m + r) * NCOLS + n] = acc[mt][r];
  }
}

extern "C" void kernel_launch(void* const* d_in, const int* in_sizes, int n_in,
                              void* d_out, int out_size, void* d_ws, size_t ws_size,
                              hipStream_t stream) {
  const float* X  = (const float*)d_in[0];
  const float* Wf = (const float*)d_in[1];
  float* out      = (float*)d_out;
  dim3 grid(NCOLS / 64, NB);
  const size_t wneed = (size_t)NB * BS * BS * sizeof(unsigned short);
  if (ws_size >= wneed) {
    unsigned* Wb = (unsigned*)d_ws;
    wcvt_kernel<<<dim3((NB * BS * BS) / (256 * 8)), 256, 0, stream>>>(Wf, Wb);
    bg_kernel<true><<<grid, 256, 0, stream>>>(X, Wf, (const unsigned short*)Wb, out);
  } else {
    bg_kernel<false><<<grid, 256, 0, stream>>>(X, Wf, nullptr, out);
  }
}

// Round 4
// 255.056 us; speedup vs baseline: 1.3684x; 1.3684x over previous
//
#include <hip/hip_runtime.h>
#include <hip/hip_bf16.h>
#include <stdint.h>

#define NCOLS 8192
#define BS    256
#define NB    16
#define NT    64

typedef float    f32x4  __attribute__((ext_vector_type(4)));
typedef short    bf16x8 __attribute__((ext_vector_type(8)));
typedef unsigned u32x4  __attribute__((ext_vector_type(4)));

// RNE-pack two fp32 into one dword of two bf16 (lo = first arg)
__device__ __forceinline__ unsigned pack2(float lo, float hi) {
  unsigned a = __builtin_bit_cast(unsigned, lo);
  unsigned b = __builtin_bit_cast(unsigned, hi);
  a += 0x7FFFu + ((a >> 16) & 1u);
  b += 0x7FFFu + ((b >> 16) & 1u);
  return (a >> 16) | (b & 0xFFFF0000u);
}

// Convert W (16x256x256 fp32) -> bf16 in ws. 8 elems/thread.
__global__ __launch_bounds__(256) void wcvt_kernel(const float* __restrict__ Wf,
                                                   unsigned* __restrict__ Wb) {
  int i = blockIdx.x * 256 + threadIdx.x;
  f32x4 a = ((const f32x4*)Wf)[2 * i];
  f32x4 c = ((const f32x4*)Wf)[2 * i + 1];
  u32x4 o;
  o.x = pack2(a.x, a.y); o.y = pack2(a.z, a.w);
  o.z = pack2(c.x, c.y); o.w = pack2(c.z, c.w);
  ((u32x4*)Wb)[i] = o;
}

// wg: block b (M=256) x NT=64 cols. X tile staged transposed+swizzled bf16 in
// 32 KiB LDS; W A-frags double-buffer-prefetched from L2-resident bf16 ws.
// Epilogue transposes acc through the dead xs buffer -> dwordx4 stores.
template<bool USE_WS>
__global__ __launch_bounds__(256, 2)
void bg_kernel(const float* __restrict__ X, const float* __restrict__ Wf,
               const unsigned short* __restrict__ Wb, float* __restrict__ out) {
  __shared__ unsigned xs[NT * 128];  // [n][kd] dwords, XOR-swizzled, 32 KiB
  const int b    = blockIdx.y;
  const int c0   = blockIdx.x * NT;
  const int t    = threadIdx.x;
  const int wid  = t >> 6;
  const int lane = t & 63;
  const int sub  = lane & 3;
  const int cg   = lane >> 2;
  const int krow = wid * 8 + sub * 2;
  const int ln16 = lane & 15;
  const int quad = lane >> 4;

  // ---- stage X tile: K=256 x NT=64, fp32 -> bf16, transpose to [n][k]
  {
    const float* xb = X + (size_t)b * BS * NCOLS + c0 + 4 * cg;
    f32x4 st[16];
#pragma unroll
    for (int p = 0; p < 8; ++p) {
      const int k0 = p * 32 + krow;
      st[2 * p]     = *(const f32x4*)(xb + (size_t)k0 * NCOLS);
      st[2 * p + 1] = *(const f32x4*)(xb + (size_t)(k0 + 1) * NCOLS);
    }
#pragma unroll
    for (int p = 0; p < 8; ++p) {
      const int kd = (p * 32 + krow) >> 1;
#pragma unroll
      for (int j = 0; j < 4; ++j) {
        const int n = 4 * cg + j;
        const int f = (n ^ (n >> 2)) & 7;
        xs[n * 128 + (kd ^ (f << 2))] = pack2(st[2 * p][j], st[2 * p + 1][j]);
      }
    }
  }
  __syncthreads();

  // ---- compute with explicit 2-deep fragment pipeline
  const size_t wbase = ((size_t)(b * BS + wid * 64 + ln16)) * BS + quad * 8;

  auto loadA = [&](int ks, int mt) -> bf16x8 {
    const size_t off = wbase + (size_t)(mt * 16) * BS + ks * 32;
    if (USE_WS) {
      return *(const bf16x8*)(Wb + off);
    } else {
      f32x4 w0 = *(const f32x4*)(Wf + off);
      f32x4 w1 = *(const f32x4*)(Wf + off + 4);
      union { unsigned u[4]; bf16x8 v; } cv;
      cv.u[0] = pack2(w0.x, w0.y); cv.u[1] = pack2(w0.z, w0.w);
      cv.u[2] = pack2(w1.x, w1.y); cv.u[3] = pack2(w1.z, w1.w);
      return cv.v;
    }
  };
  auto loadB = [&](int ks, int nt) -> bf16x8 {
    const int n = nt * 16 + ln16;
    const int f = (n ^ (n >> 2)) & 7;
    return *(const bf16x8*)(&xs[n * 128 + ((ks * 16 + quad * 4) ^ (f << 2))]);
  };

  f32x4 acc[4][4] = {};
  bf16x8 afr[2][4], bfr[2][4];
#pragma unroll
  for (int i = 0; i < 4; ++i) { afr[0][i] = loadA(0, i); bfr[0][i] = loadB(0, i); }

#pragma unroll
  for (int ks = 0; ks < 8; ++ks) {
    const int cur = ks & 1, nxt = cur ^ 1;
    if (ks < 7) {
#pragma unroll
      for (int i = 0; i < 4; ++i) { afr[nxt][i] = loadA(ks + 1, i); bfr[nxt][i] = loadB(ks + 1, i); }
    }
#pragma unroll
    for (int mt = 0; mt < 4; ++mt)
#pragma unroll
      for (int nt = 0; nt < 4; ++nt)
        acc[mt][nt] = __builtin_amdgcn_mfma_f32_16x16x32_bf16(afr[cur][mt], bfr[cur][nt],
                                                              acc[mt][nt], 0, 0, 0);
  }

  // ---- epilogue: transpose acc through xs (per-wave region, stride 68)
  __syncthreads();  // all waves done reading xs
  float* lw = (float*)xs + wid * 1088;  // 16 rows x 68 floats = 4352 B/wave
  const int erow = lane >> 4;           // 0..3
  const int ecol = 4 * (lane & 15);     // 0..60
#pragma unroll
  for (int mt = 0; mt < 4; ++mt) {
#pragma unroll
    for (int r = 0; r < 4; ++r)
#pragma unroll
      for (int nt = 0; nt < 4; ++nt)
        lw[(quad * 4 + r) * 68 + nt * 16 + ln16] = acc[mt][nt][r];
    __asm__ volatile("s_waitcnt lgkmcnt(0)" ::: "memory");
#pragma unroll
    for (int j = 0; j < 4; ++j) {
      f32x4 v = *(const f32x4*)(lw + (j * 4 + erow) * 68 + ecol);
      *(f32x4*)(out + (size_t)(b * BS + wid * 64 + mt * 16 + j * 4 + erow) * NCOLS + c0 + ecol) = v;
    }
    __asm__ volatile("s_waitcnt lgkmcnt(0)" ::: "memory");
  }
}

extern "C" void kernel_launch(void* const* d_in, const int* in_sizes, int n_in,
                              void* d_out, int out_size, void* d_ws, size_t ws_size,
                              hipStream_t stream) {
  const float* X  = (const float*)d_in[0];
  const float* Wf = (const float*)d_in[1];
  float* out      = (float*)d_out;
  dim3 grid(NCOLS / NT, NB);
  const size_t wneed = (size_t)NB * BS * BS * sizeof(unsigned short);
  if (ws_size >= wneed) {
    unsigned* Wb = (unsigned*)d_ws;
    wcvt_kernel<<<dim3((NB * BS * BS) / (256 * 8)), 256, 0, stream>>>(Wf, Wb);
    bg_kernel<true><<<grid, 256, 0, stream>>>(X, Wf, (const unsigned short*)Wb, out);
  } else {
    bg_kernel<false><<<grid, 256, 0, stream>>>(X, Wf, nullptr, out);
  }
}